// Round 8
// baseline (253.273 us; speedup 1.0000x reference)
//
#include <hip/hip_runtime.h>
#include <stdint.h>

// NVFP4Linear: M=128 (8x16), K=I=8192, N=O=8192
// d_in[0] hidden: f32 [128][8192]  (reference fp16 promoted to f32 by harness)
// d_in[1] weight: int32[8192][4096], one packed byte per int (low nibble = even k)
// d_in[2] weight_scale: f32 [8192][512] (per 16-k group)
// d_in[3] weight_scale_2: f32[1] ; d_in[4] input_scale: f32[1]
// d_out: f32 [128][8192]

typedef _Float16 half8 __attribute__((ext_vector_type(8)));
typedef float float4v __attribute__((ext_vector_type(4)));

__device__ __forceinline__ uint32_t perm_b32(uint32_t hi, uint32_t lo, uint32_t sel) {
  return __builtin_amdgcn_perm(hi, lo, sel);
}

// RNE round-trip through fp8 e4m3fn (x >= 0, finite)
__device__ __forceinline__ float e4m3_roundtrip(float x) {
  if (x < 0.015625f) {               // subnormal region: grid step 2^-9
    return __builtin_rintf(x * 512.0f) * 0.001953125f;
  }
  uint32_t u = __float_as_uint(x);
  u += 0x7FFFFu + ((u >> 20) & 1u);  // RNE to 3 mantissa bits
  u &= 0xFFF00000u;
  float y = __uint_as_float(u);
  return fminf(y, 448.0f);
}

// ---------------- Kernel 1: activation QDQ -> swizzled f16 A fragments ----------------
// A_sw fragment (kb, mb) = 64 lanes x 16B; lane l holds A[mb*16 + (l&15)][kb*32 + (l>>4)*8 + j]
__global__ __launch_bounds__(256)
void aqdq_kernel(const float* __restrict__ hs,
                 const float* __restrict__ isc,
                 uint2* __restrict__ asw) {
  const int t = blockIdx.x * 256 + threadIdx.x;   // 262144 total
  const int m = t >> 11;                          // row 0..127
  const int u = t & 2047;
  const int g = u >> 2;                           // group within row 0..511
  const int hq = u & 3;                           // quarter of group

  const float* p = hs + m * 8192 + g * 16 + hq * 4;
  float4 x = *(const float4*)p;

  float amax = fmaxf(fmaxf(fabsf(x.x), fabsf(x.y)), fmaxf(fabsf(x.z), fabsf(x.w)));
  amax = fmaxf(amax, __shfl_xor(amax, 1));
  amax = fmaxf(amax, __shfl_xor(amax, 2));

  float is = isc[0];
  float s = e4m3_roundtrip(amax / (6.0f * is));
  if (!(s > 0.0f)) s = 1.0f;
  float total = s * is;

  float xv[4] = {x.x, x.y, x.z, x.w};
  union { _Float16 h[4]; uint2 v; } qq;
#pragma unroll
  for (int i = 0; i < 4; ++i) {
    float r = xv[i] / total;         // correctly-rounded f32 div, matches jnp
    float a = fabsf(r);
    // E2M1 nearest; ties -> lower magnitude (searchsorted side='left')
    float v = (a <= 0.25f) ? 0.0f
            : (a <= 0.75f) ? 0.5f
            : (a <= 1.25f) ? 1.0f
            : (a <= 1.75f) ? 1.5f
            : (a <= 2.5f)  ? 2.0f
            : (a <= 3.5f)  ? 3.0f
            : (a <= 5.0f)  ? 4.0f : 6.0f;
    qq.h[i] = (_Float16)(copysignf(v, r) * total);  // exact in f16
  }

  const int k = g * 16 + hq * 4;
  const int kb = k >> 5;
  const int quad = (k >> 3) & 3;
  const int lane16 = (m & 15) | (quad << 4);
  const int mb = m >> 4;
  asw[((kb * 8 + mb) * 64 + lane16) * 2 + (hq & 1)] = qq.v;
}

// ---------------- fp4 pair decode: 4 packed bytes (8 codes) -> 8 scaled f16 ----------------
__device__ __forceinline__ half8 decode_scale(int4 w, float sf) {
  uint32_t t0 = perm_b32((uint32_t)w.y, (uint32_t)w.x, 0x00000400u);
  uint32_t t1 = perm_b32((uint32_t)w.w, (uint32_t)w.z, 0x04000000u);
  uint32_t b  = perm_b32(t1, t0, 0x07060100u); // byte i = codes (k2i, k2i+1)
  uint32_t ev = b & 0x0F0F0F0Fu;               // even-k nibbles
  uint32_t od = (b >> 4) & 0x0F0F0F0Fu;        // odd-k nibbles
  uint32_t evm = ev & 0x07070707u;
  uint32_t odm = od & 0x07070707u;
  uint32_t evs = (ev & 0x08080808u) << 4;      // sign -> byte-high bit (f16 bit15)
  uint32_t ods = (od & 0x08080808u) << 4;
  // f16 high bytes of {0,.5,1,1.5,2,3,4,6} = {00,38,3C,3E,40,42,44,46}
  uint32_t evh = perm_b32(0x46444240u, 0x3E3C3800u, evm) | evs;
  uint32_t odh = perm_b32(0x46444240u, 0x3E3C3800u, odm) | ods;
  union { uint32_t u[4]; half8 h; } r;
  r.u[0] = perm_b32(odh, evh, 0x04000000u) & 0xFF00FF00u; // (k1,k0)
  r.u[1] = perm_b32(odh, evh, 0x05000100u) & 0xFF00FF00u; // (k3,k2)
  r.u[2] = perm_b32(odh, evh, 0x06000200u) & 0xFF00FF00u; // (k5,k4)
  r.u[3] = perm_b32(odh, evh, 0x07000300u) & 0xFF00FF00u; // (k7,k6)
  _Float16 hsf = (_Float16)sf;
  half8 sv = {hsf, hsf, hsf, hsf, hsf, hsf, hsf, hsf};
  return r.h * sv;                              // v_pk_mul_f16 x4
}

// ---------------- Kernel 2: barrier-free register-pipelined dequant GEMM -----------------
// Grid 512 = 64 n-blocks x 8 k-parts; 256 threads (4 waves), __launch_bounds__(256,2)
// -> up to 256 VGPR, 2 blocks/CU, 8 FREE-RUNNING waves/CU (no LDS, no barriers at all).
// Wave: cols [nb*128 + wv*32, +32) x all 128 m x 1024 k (32 steps).
// Per step: 8 A-frag uint4 (L2-resident asw) + 2 weight int4 + 2 scale float2; 2 decodes;
// 16 MFMAs. Fully unrolled; A prefetched distance 1 (af[2][8]), W/scales distance 2
// (%3-rotated named buffers). All array indices compile-time (rule #20).
// MODE 0: write f32 partials [kp][128][8192]; MODE 1: unsafeAtomicAdd fallback.
template<int MODE>
__global__ __launch_bounds__(256, 2)
void gemm_kernel(const uint4* __restrict__ asw,
                 const int* __restrict__ wq,
                 const float* __restrict__ wsc,
                 const float* __restrict__ ws2p,
                 float* __restrict__ dst) {
  const int lane = threadIdx.x & 63;
  const int wv = threadIdx.x >> 6;      // wave 0..3 = col group pair
  const int quad = lane >> 4;
  const int kp = blockIdx.x & 7;        // k-part (XCD round-robin -> per-XCD A locality)
  const int nb = blockIdx.x >> 3;       // n-tile 0..63
  const int colA = nb * 128 + wv * 32 + (lane & 15);
  const int colB = colA + 16;
  const float ws2 = ws2p[0];
  const int4* wpA = (const int4*)wq + (size_t)colA * 1024 + kp * 128 + quad;
  const int4* wpB = (const int4*)wq + (size_t)colB * 1024 + kp * 128 + quad;
  const float2* spA = (const float2*)(wsc + (size_t)colA * 512 + kp * 64);
  const float2* spB = (const float2*)(wsc + (size_t)colB * 512 + kp * 64);
  const uint4* ap = asw + kp * 16384 + lane;   // frag (kb=kp*32+t, mb): ap[t*512 + mb*64]

  float4v accA[8], accB[8];
#pragma unroll
  for (int mb = 0; mb < 8; ++mb) {
    accA[mb] = (float4v){0.f, 0.f, 0.f, 0.f};
    accB[mb] = (float4v){0.f, 0.f, 0.f, 0.f};
  }

  uint4 af[2][8];          // A frags, double-buffered by t&1
  int4 wAr[3], wBr[3];     // weights, distance-2 rotation by t%3
  float2 sAr[3], sBr[3];   // scales, distance-2 rotation

  // ---- prologue: A(0); W/S(0) and W/S(1) ----
#pragma unroll
  for (int mb = 0; mb < 8; ++mb) af[0][mb] = ap[mb * 64];
  wAr[0] = wpA[0];  wBr[0] = wpB[0];
  sAr[0] = spA[0];  sBr[0] = spB[0];
  wAr[1] = wpA[4];  wBr[1] = wpB[4];
  sAr[1] = spA[1];  sBr[1] = spB[1];

#pragma unroll
  for (int t = 0; t < 32; ++t) {
    // prefetch: W/scales at distance 2, A at distance 1 (all into named regs)
    if (t + 2 < 32) {
      wAr[(t + 2) % 3] = wpA[(t + 2) * 4];
      wBr[(t + 2) % 3] = wpB[(t + 2) * 4];
      sAr[(t + 2) % 3] = spA[t + 2];
      sBr[(t + 2) % 3] = spB[t + 2];
    }
    if (t + 1 < 32) {
#pragma unroll
      for (int mb = 0; mb < 8; ++mb) af[(t + 1) & 1][mb] = ap[(t + 1) * 512 + mb * 64];
    }
    // compute step t
    float svA = ((quad & 2) ? sAr[t % 3].y : sAr[t % 3].x) * ws2;
    float svB = ((quad & 2) ? sBr[t % 3].y : sBr[t % 3].x) * ws2;
    half8 bA = decode_scale(wAr[t % 3], svA);
    half8 bB = decode_scale(wBr[t % 3], svB);
#pragma unroll
    for (int mb = 0; mb < 8; ++mb) {
      union { uint4 u; half8 h; } a_;
      a_.u = af[t & 1][mb];
      accA[mb] = __builtin_amdgcn_mfma_f32_16x16x32_f16(a_.h, bA, accA[mb], 0, 0, 0);
      accB[mb] = __builtin_amdgcn_mfma_f32_16x16x32_f16(a_.h, bB, accB[mb], 0, 0, 0);
    }
  }

  // Epilogue. C/D layout: n = lane&15, m = quad*4 + reg (verified m89/m91)
  if (MODE == 0) {
    float* ppA = dst + ((size_t)kp << 20) + colA;
    float* ppB = dst + ((size_t)kp << 20) + colB;
#pragma unroll
    for (int mb = 0; mb < 8; ++mb) {
      const int mrow = mb * 16 + quad * 4;
#pragma unroll
      for (int r = 0; r < 4; ++r) {
        ppA[(size_t)(mrow + r) * 8192] = accA[mb][r];
        ppB[(size_t)(mrow + r) * 8192] = accB[mb][r];
      }
    }
  } else {
#pragma unroll
    for (int mb = 0; mb < 8; ++mb) {
      const int mrow = mb * 16 + quad * 4;
#pragma unroll
      for (int r = 0; r < 4; ++r) {
        unsafeAtomicAdd(&dst[(size_t)(mrow + r) * 8192 + colA], accA[mb][r]);
        unsafeAtomicAdd(&dst[(size_t)(mrow + r) * 8192 + colB], accB[mb][r]);
      }
    }
  }
}

// ---------------- Kernel 3: k-part reduction (MODE-0 path) ----------------
__global__ __launch_bounds__(256)
void reduce_kernel(const float4* __restrict__ part, float4* __restrict__ out) {
  const int i = blockIdx.x * 256 + threadIdx.x;   // 262144 float4 = 1M floats
  float4 s = part[i];
#pragma unroll
  for (int p = 1; p < 8; ++p) {
    float4 b = part[(size_t)p * 262144 + i];
    s.x += b.x; s.y += b.y; s.z += b.z; s.w += b.w;
  }
  out[i] = s;
}

extern "C" void kernel_launch(void* const* d_in, const int* in_sizes, int n_in,
                              void* d_out, int out_size, void* d_ws, size_t ws_size,
                              hipStream_t stream) {
  (void)in_sizes; (void)n_in; (void)out_size;
  const float* hs  = (const float*)d_in[0];   // f32 [128][8192]
  const int* wq    = (const int*)d_in[1];     // int32 [8192][4096]
  const float* wsc = (const float*)d_in[2];   // f32 [8192][512]
  const float* ws2 = (const float*)d_in[3];   // f32 [1]
  const float* isc = (const float*)d_in[4];   // f32 [1]
  float* out       = (float*)d_out;           // f32 [128][8192]
  uint2* asw2      = (uint2*)d_ws;            // 2 MiB swizzled f16 A fragments (8B store view)
  const uint4* asw4 = (const uint4*)d_ws;     // same buffer, 16B fragment view

  aqdq_kernel<<<1024, 256, 0, stream>>>(hs, isc, asw2);

  const size_t need = ((size_t)2 << 20) + ((size_t)32 << 20);  // asw + partials
  if (ws_size >= need) {
    float* part = (float*)((char*)d_ws + ((size_t)2 << 20));   // f32 [8][128][8192]
    gemm_kernel<0><<<512, 256, 0, stream>>>(asw4, wq, wsc, ws2, part);
    reduce_kernel<<<1024, 256, 0, stream>>>((const float4*)part, (float4*)out);
  } else {
    hipMemsetAsync(out, 0, (size_t)128 * 8192 * 4, stream);
    gemm_kernel<1><<<512, 256, 0, stream>>>(asw4, wq, wsc, ws2, out);
  }
}

// Round 10
// 248.514 us; speedup vs baseline: 1.0192x; 1.0192x over previous
//
#include <hip/hip_runtime.h>
#include <stdint.h>

// NVFP4Linear: M=128 (8x16), K=I=8192, N=O=8192
// d_in[0] hidden: f32 [128][8192]  (reference fp16 promoted to f32 by harness)
// d_in[1] weight: int32[8192][4096], one packed byte per int (low nibble = even k)
// d_in[2] weight_scale: f32 [8192][512] (per 16-k group)
// d_in[3] weight_scale_2: f32[1] ; d_in[4] input_scale: f32[1]
// d_out: f32 [128][8192]

typedef _Float16 half8 __attribute__((ext_vector_type(8)));
typedef float float4v __attribute__((ext_vector_type(4)));

__device__ __forceinline__ uint32_t perm_b32(uint32_t hi, uint32_t lo, uint32_t sel) {
  return __builtin_amdgcn_perm(hi, lo, sel);
}

// Async global->LDS DMA, 16B per lane. LDS dest must be the WAVE-UNIFORM base;
// HW adds lane*16. Global src is per-lane.
__device__ __forceinline__ void load_lds16(const uint4* g, uint4* l) {
  __builtin_amdgcn_global_load_lds((const __attribute__((address_space(1))) void*)g,
                                   (__attribute__((address_space(3))) void*)l,
                                   16, 0, 0);
}

// pack low bytes of 4 int32 -> u32 [x0,y0,z0,w0]  (3 v_perm)
__device__ __forceinline__ uint32_t pack4(int4 w) {
  uint32_t t0 = perm_b32((uint32_t)w.y, (uint32_t)w.x, 0x00000400u);
  uint32_t t1 = perm_b32((uint32_t)w.w, (uint32_t)w.z, 0x04000000u);
  return perm_b32(t1, t0, 0x07060100u);
}

// RNE round-trip through fp8 e4m3fn (x >= 0, finite)
__device__ __forceinline__ float e4m3_roundtrip(float x) {
  if (x < 0.015625f) {               // subnormal region: grid step 2^-9
    return __builtin_rintf(x * 512.0f) * 0.001953125f;
  }
  uint32_t u = __float_as_uint(x);
  u += 0x7FFFFu + ((u >> 20) & 1u);  // RNE to 3 mantissa bits
  u &= 0xFFF00000u;
  float y = __uint_as_float(u);
  return fminf(y, 448.0f);
}

// ---------------- Kernel 1: activation QDQ -> swizzled f16 A fragments ----------------
// A_sw fragment (kb, mb) = 64 lanes x 16B; lane l holds A[mb*16 + (l&15)][kb*32 + (l>>4)*8 + j]
__global__ __launch_bounds__(256)
void aqdq_kernel(const float* __restrict__ hs,
                 const float* __restrict__ isc,
                 uint2* __restrict__ asw) {
  const int t = blockIdx.x * 256 + threadIdx.x;   // 262144 total
  const int m = t >> 11;                          // row 0..127
  const int u = t & 2047;
  const int g = u >> 2;                           // group within row 0..511
  const int hq = u & 3;                           // quarter of group

  const float* p = hs + m * 8192 + g * 16 + hq * 4;
  float4 x = *(const float4*)p;

  float amax = fmaxf(fmaxf(fabsf(x.x), fabsf(x.y)), fmaxf(fabsf(x.z), fabsf(x.w)));
  amax = fmaxf(amax, __shfl_xor(amax, 1));
  amax = fmaxf(amax, __shfl_xor(amax, 2));

  float is = isc[0];
  float s = e4m3_roundtrip(amax / (6.0f * is));
  if (!(s > 0.0f)) s = 1.0f;
  float total = s * is;

  float xv[4] = {x.x, x.y, x.z, x.w};
  union { _Float16 h[4]; uint2 v; } qq;
#pragma unroll
  for (int i = 0; i < 4; ++i) {
    float r = xv[i] / total;         // correctly-rounded f32 div, matches jnp
    float a = fabsf(r);
    // E2M1 nearest; ties -> lower magnitude (searchsorted side='left')
    float v = (a <= 0.25f) ? 0.0f
            : (a <= 0.75f) ? 0.5f
            : (a <= 1.25f) ? 1.0f
            : (a <= 1.75f) ? 1.5f
            : (a <= 2.5f)  ? 2.0f
            : (a <= 3.5f)  ? 3.0f
            : (a <= 5.0f)  ? 4.0f : 6.0f;
    qq.h[i] = (_Float16)(copysignf(v, r) * total);  // exact in f16
  }

  const int k = g * 16 + hq * 4;
  const int kb = k >> 5;
  const int quad = (k >> 3) & 3;
  const int lane16 = (m & 15) | (quad << 4);
  const int mb = m >> 4;
  asw[((kb * 8 + mb) * 64 + lane16) * 2 + (hq & 1)] = qq.v;
}

// ---------------- fp4 decode: packed u32 (4 bytes = 8 codes) -> 8 scaled f16 ----------------
__device__ __forceinline__ half8 decode_u32(uint32_t b, float sf) {
  uint32_t ev = b & 0x0F0F0F0Fu;               // even-k nibbles
  uint32_t od = (b >> 4) & 0x0F0F0F0Fu;        // odd-k nibbles
  uint32_t evm = ev & 0x07070707u;
  uint32_t odm = od & 0x07070707u;
  uint32_t evs = (ev & 0x08080808u) << 4;      // sign -> byte-high bit (f16 bit15)
  uint32_t ods = (od & 0x08080808u) << 4;
  // f16 high bytes of {0,.5,1,1.5,2,3,4,6} = {00,38,3C,3E,40,42,44,46}
  uint32_t evh = perm_b32(0x46444240u, 0x3E3C3800u, evm) | evs;
  uint32_t odh = perm_b32(0x46444240u, 0x3E3C3800u, odm) | ods;
  union { uint32_t u[4]; half8 h; } r;
  r.u[0] = perm_b32(odh, evh, 0x04000000u) & 0xFF00FF00u; // (k1,k0)
  r.u[1] = perm_b32(odh, evh, 0x05000100u) & 0xFF00FF00u; // (k3,k2)
  r.u[2] = perm_b32(odh, evh, 0x06000200u) & 0xFF00FF00u; // (k5,k4)
  r.u[3] = perm_b32(odh, evh, 0x07000300u) & 0xFF00FF00u; // (k7,k6)
  _Float16 hsf = (_Float16)sf;
  half8 sv = {hsf, hsf, hsf, hsf, hsf, hsf, hsf, hsf};
  return r.h * sv;                              // v_pk_mul_f16 x4
}

// ---------------- Kernel 2: linear-staged fused dequant GEMM (__syncthreads hardened) -----
// Grid 2048 = 128 n-blocks x 16 k-parts; 256 threads (4 waves); LDS 40 KiB -> 4 blocks/CU.
// Block (nb,ks): cols [nb*64, +64), k in [ks*512, +512) (16 MFMA steps). Wave wv: 16 cols.
// WEIGHT: staged ONCE in prologue. Per col: its 512-k slice = ONE fully-contiguous 1 KiB
// load (64 lanes x int4; lane l covers k window l*8). pack4 -> u32 payload ->
// bank-swizzled per-wave LDS tile: idx = wv*1024 + c*64 + (((l>>2)^(c&7))<<2) + (l&3).
// SCALES: 2 float4/lane (128 B contiguous per col) -> swizzled per-wave LDS (8 KiB).
// MAIN LOOP: zero global weight traffic. Per step T: {__syncthreads() [full drain certifies
// A(T) DMA for all waves + frees buf (T+1)&1]; issue 2 A-DMAs for T+1; 8 ds_read_b128 A +
// 1 b32 W + 1 b32 S + decode + 8 MFMA}. All W/S register deps are compiler-tracked; the
// only DMA guard needed is the __syncthreads drain (m97-verified idiom).
// MODE 0: write f32 partials [ks][128][8192]; MODE 1: unsafeAtomicAdd fallback.
template<int MODE>
__global__ __launch_bounds__(256, 4)
void gemm_kernel(const uint4* __restrict__ asw,
                 const int* __restrict__ wq,
                 const float* __restrict__ wsc,
                 const float* __restrict__ ws2p,
                 float* __restrict__ dst) {
  __shared__ uint4 abuf[2][8][64];      // 16 KiB A ring-2 (frag layout)
  __shared__ uint32_t wlds[4096];       // 16 KiB packed-weight tile (per-wave, swizzled)
  __shared__ float slds[2048];          // 8 KiB scale tile (per-wave, swizzled)
  const int lane = threadIdx.x & 63;
  const int wv = threadIdx.x >> 6;      // wave 0..3 = 16-col group
  const int quad = lane >> 4;
  const int ks = blockIdx.x & 15;       // k-part (512 k)
  const int nb = blockIdx.x >> 4;       // n-tile 0..127 (64 cols)
  const int colg0 = nb * 64 + wv * 16;  // wave's col base
  const int col = colg0 + (lane & 15);
  const float ws2 = ws2p[0];
  const int4* wr = (const int4*)wq;     // col*1024 int4 per row; ks-slice = 64 int4
  const uint4* apA = asw + ((size_t)(ks * 16) * 8 + wv * 2) * 64 + lane;      // mb=wv*2
  const uint4* apB = apA + 64;                                                // mb=wv*2+1
  const int sW = lane >> 2;             // staging: step of this lane's int4
  const int qW = lane & 3;              // staging: quad

  float4v acc[8];
#pragma unroll
  for (int mb = 0; mb < 8; ++mb) acc[mb] = (float4v){0.f, 0.f, 0.f, 0.f};

  // ---- prologue: A(0) DMA; stage W (16 cols, 1 KiB contiguous each) + S ----
  load_lds16(apA, &abuf[0][wv * 2][0]);
  load_lds16(apB, &abuf[0][wv * 2 + 1][0]);

  int4 wr0, wr1, wr2, wr3, wr4, wr5, wr6, wr7;
#define W_ISSUE4(R0, R1, R2, R3, CB)                                              \
  R0 = wr[(size_t)(colg0 + (CB) + 0) * 1024 + ks * 64 + lane];                    \
  R1 = wr[(size_t)(colg0 + (CB) + 1) * 1024 + ks * 64 + lane];                    \
  R2 = wr[(size_t)(colg0 + (CB) + 2) * 1024 + ks * 64 + lane];                    \
  R3 = wr[(size_t)(colg0 + (CB) + 3) * 1024 + ks * 64 + lane];                    \
  __builtin_amdgcn_sched_barrier(0);

#define W_WRITE4(R0, R1, R2, R3, CB)                                              \
  {                                                                               \
    uint32_t b0 = pack4(R0), b1 = pack4(R1), b2 = pack4(R2), b3 = pack4(R3);      \
    wlds[wv * 1024 + ((CB) + 0) * 64 + ((sW ^ (((CB) + 0) & 7)) << 2) + qW] = b0; \
    wlds[wv * 1024 + ((CB) + 1) * 64 + ((sW ^ (((CB) + 1) & 7)) << 2) + qW] = b1; \
    wlds[wv * 1024 + ((CB) + 2) * 64 + ((sW ^ (((CB) + 2) & 7)) << 2) + qW] = b2; \
    wlds[wv * 1024 + ((CB) + 3) * 64 + ((sW ^ (((CB) + 3) & 7)) << 2) + qW] = b3; \
    __builtin_amdgcn_sched_barrier(0);                                            \
  }

  W_ISSUE4(wr0, wr1, wr2, wr3, 0)
  W_ISSUE4(wr4, wr5, wr6, wr7, 4)
  W_WRITE4(wr0, wr1, wr2, wr3, 0)       // compiler inserts the needed vmcnt waits
  W_ISSUE4(wr0, wr1, wr2, wr3, 8)
  W_WRITE4(wr4, wr5, wr6, wr7, 4)
  W_ISSUE4(wr4, wr5, wr6, wr7, 12)
  W_WRITE4(wr0, wr1, wr2, wr3, 8)
  // scales: lane l covers col (l>>2), groups (l&3)*8 .. +7  (128 B contiguous per col)
  {
    const float* sb = wsc + (size_t)(colg0 + (lane >> 2)) * 512 + ks * 32 + (lane & 3) * 8;
    float4v s0 = *(const float4v*)sb;
    float4v s1 = *(const float4v*)(sb + 4);
    W_WRITE4(wr4, wr5, wr6, wr7, 12)
    const int cS = lane >> 2;
    const int G0 = (lane & 3) * 2;
    *(float4v*)&slds[wv * 512 + cS * 32 + ((G0 ^ (cS & 7)) << 2)] = s0;
    *(float4v*)&slds[wv * 512 + cS * 32 + (((G0 | 1) ^ (cS & 7)) << 2)] = s1;
  }
#undef W_ISSUE4
#undef W_WRITE4

  // ---- main loop: 16 steps, ring-2 A, full-drain __syncthreads per step ----
#define STEP(T)                                                                   \
  {                                                                               \
    __syncthreads();   /* drains vmcnt+lgkm: certifies A(T) in abuf[(T)&1] for   */ \
                       /* ALL waves; all reads of abuf[(T+1)&1] (step T-1) done  */ \
    __builtin_amdgcn_sched_barrier(0);                                            \
    if ((T) < 15) {                                                               \
      load_lds16(apA + ((T) + 1) * 512, &abuf[((T) + 1) & 1][wv * 2][0]);         \
      load_lds16(apB + ((T) + 1) * 512, &abuf[((T) + 1) & 1][wv * 2 + 1][0]);     \
    }                                                                             \
    __builtin_amdgcn_sched_barrier(0);                                            \
    uint4 af[8];                                                                  \
    _Pragma("unroll")                                                             \
    for (int mb = 0; mb < 8; ++mb) af[mb] = abuf[(T) & 1][mb][lane];              \
    uint32_t wb = wlds[wv * 1024 + (lane & 15) * 64 +                             \
                       (((T) ^ (lane & 7)) << 2) + (lane >> 4)];                  \
    const int g_ = 2 * (T) + (quad >> 1);                                         \
    float sc = slds[wv * 512 + (lane & 15) * 32 +                                 \
                    (((g_ >> 2) ^ (lane & 7)) << 2) + (g_ & 3)] * ws2;            \
    half8 bA = decode_u32(wb, sc);                                                \
    _Pragma("unroll")                                                             \
    for (int mb = 0; mb < 8; ++mb) {                                              \
      union { uint4 u; half8 h; } a_;                                             \
      a_.u = af[mb];                                                              \
      acc[mb] = __builtin_amdgcn_mfma_f32_16x16x32_f16(a_.h, bA, acc[mb], 0, 0, 0);\
    }                                                                             \
  }

  STEP(0)  STEP(1)  STEP(2)  STEP(3)
  STEP(4)  STEP(5)  STEP(6)  STEP(7)
  STEP(8)  STEP(9)  STEP(10) STEP(11)
  STEP(12) STEP(13) STEP(14) STEP(15)
#undef STEP

  // Epilogue. C/D layout: n = lane&15, m = quad*4 + reg (verified m89/m91)
  if (MODE == 0) {
    float* pp = dst + ((size_t)ks << 20) + col;
#pragma unroll
    for (int mb = 0; mb < 8; ++mb) {
      const int mrow = mb * 16 + quad * 4;
#pragma unroll
      for (int r = 0; r < 4; ++r) pp[(size_t)(mrow + r) * 8192] = acc[mb][r];
    }
  } else {
#pragma unroll
    for (int mb = 0; mb < 8; ++mb) {
      const int mrow = mb * 16 + quad * 4;
#pragma unroll
      for (int r = 0; r < 4; ++r)
        unsafeAtomicAdd(&dst[(size_t)(mrow + r) * 8192 + col], acc[mb][r]);
    }
  }
}

// ---------------- Kernel 3: k-part reduction (MODE-0 path, 16 parts) ----------------
__global__ __launch_bounds__(256)
void reduce_kernel(const float4* __restrict__ part, float4* __restrict__ out) {
  const int i = blockIdx.x * 256 + threadIdx.x;   // 262144 float4 = 1M floats
  float4 s = part[i];
#pragma unroll
  for (int p = 1; p < 16; ++p) {
    float4 b = part[(size_t)p * 262144 + i];
    s.x += b.x; s.y += b.y; s.z += b.z; s.w += b.w;
  }
  out[i] = s;
}

extern "C" void kernel_launch(void* const* d_in, const int* in_sizes, int n_in,
                              void* d_out, int out_size, void* d_ws, size_t ws_size,
                              hipStream_t stream) {
  (void)in_sizes; (void)n_in; (void)out_size;
  const float* hs  = (const float*)d_in[0];   // f32 [128][8192]
  const int* wq    = (const int*)d_in[1];     // int32 [8192][4096]
  const float* wsc = (const float*)d_in[2];   // f32 [8192][512]
  const float* ws2 = (const float*)d_in[3];   // f32 [1]
  const float* isc = (const float*)d_in[4];   // f32 [1]
  float* out       = (float*)d_out;           // f32 [128][8192]
  uint2* asw2      = (uint2*)d_ws;            // 2 MiB swizzled f16 A fragments (8B store view)
  const uint4* asw4 = (const uint4*)d_ws;     // same buffer, 16B fragment view

  aqdq_kernel<<<1024, 256, 0, stream>>>(hs, isc, asw2);

  const size_t need = ((size_t)2 << 20) + ((size_t)64 << 20);  // asw + 16 partials
  if (ws_size >= need) {
    float* part = (float*)((char*)d_ws + ((size_t)2 << 20));   // f32 [16][128][8192]
    gemm_kernel<0><<<2048, 256, 0, stream>>>(asw4, wq, wsc, ws2, part);
    reduce_kernel<<<1024, 256, 0, stream>>>((const float4*)part, (float4*)out);
  } else {
    hipMemsetAsync(out, 0, (size_t)128 * 8192 * 4, stream);
    gemm_kernel<1><<<2048, 256, 0, stream>>>(asw4, wq, wsc, ws2, out);
  }
}